// Round 20
// baseline (92.624 us; speedup 1.0000x reference)
//
#include <hip/hip_runtime.h>

// B=4, N=4096, D=128 fixed by the reference setup.
// d_ws layout: [0, 4MiB) h as bf16 bits (ushort), [4MiB, +64KiB) sq fp32.

typedef float  f32x4   __attribute__((ext_vector_type(4)));
typedef float  f32x16  __attribute__((ext_vector_type(16)));
typedef short  bf16x8  __attribute__((ext_vector_type(8)));

__device__ inline float bf2f(unsigned int u) {
    union { unsigned int i; float f; } c; c.i = u << 16; return c.f;
}
__device__ inline unsigned short f2bf(float f) {
    union { float f; unsigned int i; } c; c.f = f;
    unsigned int r = c.i + 0x7fffu + ((c.i >> 16) & 1u);   // RNE
    return (unsigned short)(r >> 16);
}

// ---------------- Kernel A: h = bf16(x @ W^T + b), plus sq[row] = ||h_row||^2 ----
#define KA_ROWS 32
__global__ __launch_bounds__(256) void proj_kernel(
    const float* __restrict__ x, const float* __restrict__ W,
    const float* __restrict__ bias, unsigned short* __restrict__ h,
    float* __restrict__ sq)
{
    __shared__ __align__(16) unsigned short W5[32 * 4 * 32 * 4]; // 32 KiB
    __shared__ float xs[KA_ROWS][132];
    const int t = threadIdx.x;
    const long r0 = (long)blockIdx.x * KA_ROWS;

    for (int q = t; q < 4096; q += 256) {
        float4 w4 = ((const float4*)W)[q];
        int e = q >> 5, d4 = q & 31;
        int eb = e >> 2, ei = e & 3;
        ushort4 o;
        o.x = f2bf(w4.x); o.y = f2bf(w4.y); o.z = f2bf(w4.z); o.w = f2bf(w4.w);
        *(ushort4*)&W5[d4 * 256 + ei * 64 + ((eb ^ d4) & 31) * 4] = o;
    }
    const float4* xsrc = (const float4*)(x + r0 * 128);
    for (int q = t; q < KA_ROWS * 32; q += 256) {
        float4 v = xsrc[q];
        int r = q >> 5, d = (q & 31) << 2;
        xs[r][d] = v.x; xs[r][d + 1] = v.y; xs[r][d + 2] = v.z; xs[r][d + 3] = v.w;
    }
    __syncthreads();

    const int eb = t & 31, rb = t >> 5;
    const int e0 = eb * 4, rr0 = rb * 4;

    float acc_[4][4];
    #pragma unroll
    for (int ei = 0; ei < 4; ++ei) {
        float bv = bias[e0 + ei];
        #pragma unroll
        for (int ri = 0; ri < 4; ++ri) acc_[ri][ei] = bv;
    }

    for (int d4 = 0; d4 < 32; ++d4) {
        float wv[4][4];
        #pragma unroll
        for (int ei = 0; ei < 4; ++ei) {
            ushort4 u = *(const ushort4*)&W5[d4 * 256 + ei * 64 + ((eb ^ d4) & 31) * 4];
            wv[ei][0] = bf2f(u.x); wv[ei][1] = bf2f(u.y);
            wv[ei][2] = bf2f(u.z); wv[ei][3] = bf2f(u.w);
        }
        #pragma unroll
        for (int ri = 0; ri < 4; ++ri) {
            float4 xv = *(const float4*)&xs[rr0 + ri][d4 * 4];
            #pragma unroll
            for (int ei = 0; ei < 4; ++ei) {
                acc_[ri][ei] = fmaf(xv.x, wv[ei][0],
                               fmaf(xv.y, wv[ei][1],
                               fmaf(xv.z, wv[ei][2],
                               fmaf(xv.w, wv[ei][3], acc_[ri][ei]))));
            }
        }
    }

    float s[4] = {0.f, 0.f, 0.f, 0.f};
    #pragma unroll
    for (int ri = 0; ri < 4; ++ri) {
        ushort4 o;
        float v0 = bf2f(o.x = f2bf(acc_[ri][0]));
        float v1 = bf2f(o.y = f2bf(acc_[ri][1]));
        float v2 = bf2f(o.z = f2bf(acc_[ri][2]));
        float v3 = bf2f(o.w = f2bf(acc_[ri][3]));
        s[ri] = v0 * v0 + v1 * v1 + v2 * v2 + v3 * v3;
        *(ushort4*)&h[(r0 + rr0 + ri) * 128 + e0] = o;
    }
    #pragma unroll
    for (int ri = 0; ri < 4; ++ri) {
        #pragma unroll
        for (int m = 16; m > 0; m >>= 1) s[ri] += __shfl_xor(s[ri], m, 64);
    }
    if (eb == 0) {
        #pragma unroll
        for (int ri = 0; ri < 4; ++ri) sq[r0 + rr0 + ri] = s[ri];
    }
}

// ---------------- Kernel B: barrier-free gram, prefetched B-frags --------------
// R6's wave-independent structure with BOTH of its poisons removed:
// (1) sq_j in LDS (ds_read = lgkmcnt, never drains the store queue), sq_i +
//     A-frags in registers — zero global VGPR loads interleaved with stores;
// (2) B-frags register-double-buffered ONE js AHEAD: LOADB(js+1) issues
//     BEFORE iteration js's stores, so MFMA(js+1) waits on loads OLDER than
//     the stores — counted vmcnt retires loads, stores stay in flight.
// One prologue barrier; zero loop barriers; nt stores fire-and-forget to
// s_endpgm. 32i x 512j strip/wave; fully unrolled js pairs (static indices).
// XCD affinity keeps each batch's 1 MiB h-panel L2-resident (R7: FETCH 4 MB).
__global__ __launch_bounds__(256, 3) void gram_kernel(
    const unsigned short* __restrict__ h, const float* __restrict__ sq,
    float* __restrict__ out)
{
    __shared__ float sqj_s[2048];                     // block's j-range sq (8 KiB)
    const int bid = blockIdx.x;                       // 1024 blocks
    const int xcd = bid & 7;
    const int bb  = xcd >> 1;                         // batch -> XCD pair
    const int local = ((bid >> 3) << 1) | (xcd & 1);  // 0..255 within batch
    const int i0l = (local >> 1) * 32;                // i-strip (128 per batch)
    const int jr  = local & 1;
    const int t = threadIdx.x, w = t >> 6, lane = t & 63;
    const int l31 = lane & 31, lh = lane >> 5;
    const int jblk = jr * 2048;                       // block j base (batch-local)
    const int j0 = jblk + w * 512;                    // wave j base
    const long jbase = (long)bb * 4096;
    const long ibase = jbase + i0l;
    const char* hb = (const char*)h;

    // stage sq_j for the block's 2048 cols (coalesced; before any stores)
    #pragma unroll
    for (int q = 0; q < 8; ++q)
        sqj_s[q * 256 + t] = sq[jbase + jblk + q * 256 + t];

    // A-frags (32x32x16 A layout: row = lane&31, k-chunk = ks*2+lh)
    bf16x8 af[8];
    {
        const char* abase = hb + ((ibase + l31) << 8);
        #pragma unroll
        for (int ks = 0; ks < 8; ++ks)
            af[ks] = *(const bf16x8*)(abase + ((ks * 2 + lh) << 4));
    }
    // sq_i per acc reg (C/D row = (reg&3)+8*(reg>>2)+4*lh)
    float sqi_r[16];
    #pragma unroll
    for (int reg = 0; reg < 16; ++reg)
        sqi_r[reg] = sq[ibase + (reg & 3) + 8 * (reg >> 2) + 4 * lh];

    float* ob = out + ((size_t)bb << 24) + ((size_t)i0l << 12) + j0 + l31;

    __syncthreads();   // sqj_s ready (no stores outstanding yet)

    #define LOADB(dst, js_)                                                    \
        { const char* bp_ = hb + ((jbase + j0 + (js_) * 32 + l31) << 8);       \
          _Pragma("unroll")                                                    \
          for (int ks = 0; ks < 8; ++ks)                                       \
              dst[ks] = *(const bf16x8*)(bp_ + ((ks * 2 + lh) << 4)); }

    #define CSTORE(bg, js_)                                                    \
        { f32x16 acc = {};                                                     \
          _Pragma("unroll")                                                    \
          for (int ks = 0; ks < 8; ++ks)                                       \
              acc = __builtin_amdgcn_mfma_f32_32x32x16_bf16(                   \
                  af[ks], bg[ks], acc, 0, 0, 0);                               \
          const float sqj = sqj_s[w * 512 + (js_) * 32 + l31];                 \
          const int jcol = j0 + (js_) * 32 + l31;                              \
          _Pragma("unroll")                                                    \
          for (int reg = 0; reg < 16; ++reg) {                                 \
              const int rl = (reg & 3) + 8 * (reg >> 2) + 4 * lh;              \
              float d2 = fmaxf(fmaf(acc[reg], -2.0f, sqi_r[reg] + sqj), 0.0f); \
              float val = __expf(-__builtin_amdgcn_sqrtf(d2));                 \
              if (i0l + rl == jcol) val = 1.0f;                                \
              __builtin_nontemporal_store(val, ob + rl * 4096 + (js_) * 32);   \
          } }

    bf16x8 bgA[8], bgB[8];
    LOADB(bgA, 0);
    #pragma unroll
    for (int js = 0; js < 16; js += 2) {
        LOADB(bgB, js + 1);            // issued BEFORE CSTORE(js)'s stores
        CSTORE(bgA, js);
        if (js + 2 < 16) LOADB(bgA, js + 2);   // before CSTORE(js+1)'s stores
        CSTORE(bgB, js + 1);
    }
    #undef LOADB
    #undef CSTORE
}

extern "C" void kernel_launch(void* const* d_in, const int* in_sizes, int n_in,
                              void* d_out, int out_size, void* d_ws, size_t ws_size,
                              hipStream_t stream) {
    const float* x = (const float*)d_in[0];   // [4,4096,128]
    const float* W = (const float*)d_in[1];   // [128,128]
    const float* b = (const float*)d_in[2];   // [128]
    float* out = (float*)d_out;               // [4,4096,4096]

    unsigned short* h = (unsigned short*)d_ws;                       // 16384*128 bf16
    float* sq = (float*)((char*)d_ws + (size_t)16384 * 128 * 2);     // 16384 fp32

    proj_kernel<<<dim3(16384 / KA_ROWS), dim3(256), 0, stream>>>(x, W, b, h, sq);
    gram_kernel<<<dim3(1024), dim3(256), 0, stream>>>(h, sq, out);
}

// Round 21
// 76.035 us; speedup vs baseline: 1.2182x; 1.2182x over previous
//
#include <hip/hip_runtime.h>

// B=4, N=4096, D=128 fixed by the reference setup.
// d_ws layout: [0, 4MiB) h as bf16 bits (ushort), [4MiB, +64KiB) sq fp32.

typedef float  f32x4   __attribute__((ext_vector_type(4)));
typedef float  f32x16  __attribute__((ext_vector_type(16)));
typedef short  bf16x8  __attribute__((ext_vector_type(8)));

__device__ inline float bf2f(unsigned int u) {
    union { unsigned int i; float f; } c; c.i = u << 16; return c.f;
}
__device__ inline unsigned short f2bf(float f) {
    union { float f; unsigned int i; } c; c.f = f;
    unsigned int r = c.i + 0x7fffu + ((c.i >> 16) & 1u);   // RNE
    return (unsigned short)(r >> 16);
}

// ---------------- Kernel A: h = bf16(x @ W^T + b), plus sq[row] = ||h_row||^2 ----
#define KA_ROWS 32
__global__ __launch_bounds__(256) void proj_kernel(
    const float* __restrict__ x, const float* __restrict__ W,
    const float* __restrict__ bias, unsigned short* __restrict__ h,
    float* __restrict__ sq)
{
    __shared__ __align__(16) unsigned short W5[32 * 4 * 32 * 4]; // 32 KiB
    __shared__ float xs[KA_ROWS][132];
    const int t = threadIdx.x;
    const long r0 = (long)blockIdx.x * KA_ROWS;

    for (int q = t; q < 4096; q += 256) {
        float4 w4 = ((const float4*)W)[q];
        int e = q >> 5, d4 = q & 31;
        int eb = e >> 2, ei = e & 3;
        ushort4 o;
        o.x = f2bf(w4.x); o.y = f2bf(w4.y); o.z = f2bf(w4.z); o.w = f2bf(w4.w);
        *(ushort4*)&W5[d4 * 256 + ei * 64 + ((eb ^ d4) & 31) * 4] = o;
    }
    const float4* xsrc = (const float4*)(x + r0 * 128);
    for (int q = t; q < KA_ROWS * 32; q += 256) {
        float4 v = xsrc[q];
        int r = q >> 5, d = (q & 31) << 2;
        xs[r][d] = v.x; xs[r][d + 1] = v.y; xs[r][d + 2] = v.z; xs[r][d + 3] = v.w;
    }
    __syncthreads();

    const int eb = t & 31, rb = t >> 5;
    const int e0 = eb * 4, rr0 = rb * 4;

    float acc_[4][4];
    #pragma unroll
    for (int ei = 0; ei < 4; ++ei) {
        float bv = bias[e0 + ei];
        #pragma unroll
        for (int ri = 0; ri < 4; ++ri) acc_[ri][ei] = bv;
    }

    for (int d4 = 0; d4 < 32; ++d4) {
        float wv[4][4];
        #pragma unroll
        for (int ei = 0; ei < 4; ++ei) {
            ushort4 u = *(const ushort4*)&W5[d4 * 256 + ei * 64 + ((eb ^ d4) & 31) * 4];
            wv[ei][0] = bf2f(u.x); wv[ei][1] = bf2f(u.y);
            wv[ei][2] = bf2f(u.z); wv[ei][3] = bf2f(u.w);
        }
        #pragma unroll
        for (int ri = 0; ri < 4; ++ri) {
            float4 xv = *(const float4*)&xs[rr0 + ri][d4 * 4];
            #pragma unroll
            for (int ei = 0; ei < 4; ++ei) {
                acc_[ri][ei] = fmaf(xv.x, wv[ei][0],
                               fmaf(xv.y, wv[ei][1],
                               fmaf(xv.z, wv[ei][2],
                               fmaf(xv.w, wv[ei][3], acc_[ri][ei]))));
            }
        }
    }

    float s[4] = {0.f, 0.f, 0.f, 0.f};
    #pragma unroll
    for (int ri = 0; ri < 4; ++ri) {
        ushort4 o;
        float v0 = bf2f(o.x = f2bf(acc_[ri][0]));
        float v1 = bf2f(o.y = f2bf(acc_[ri][1]));
        float v2 = bf2f(o.z = f2bf(acc_[ri][2]));
        float v3 = bf2f(o.w = f2bf(acc_[ri][3]));
        s[ri] = v0 * v0 + v1 * v1 + v2 * v2 + v3 * v3;
        *(ushort4*)&h[(r0 + rr0 + ri) * 128 + e0] = o;
    }
    #pragma unroll
    for (int ri = 0; ri < 4; ++ri) {
        #pragma unroll
        for (int m = 16; m > 0; m >>= 1) s[ri] += __shfl_xor(s[ri], m, 64);
    }
    if (eb == 0) {
        #pragma unroll
        for (int ri = 0; ri < 4; ++ri) sq[r0 + rr0 + ri] = s[ri];
    }
}

// ---------------- Kernel B: 128x128 tile, 4 blocks/CU (33 KiB LDS) -------------
// R19 champion with the i-panel moved from LDS to per-wave register A-frags:
// LDS = one 32 KiB j-panel + 512 B sqj -> FOUR blocks co-resident per CU.
// Deeper co-residency desynchronizes phases: store drains of some blocks ride
// under stage/MFMA/trans of others. All proven mechanisms kept: reg-staged
// L2-allocating loads, both-sides XOR swizzle, XCD affinity, vmcnt-clean
// epilogue (sqj via ds_read, sqi in regs; zero global loads after barrier),
// nt dword stores, one barrier. Each of 4 waves: 32 i-rows x 128 j-cols as
// 4 unrolled 32-col chunks with acc reuse (~116 VGPR).
__global__ __launch_bounds__(256, 4) void gram_kernel(
    const unsigned short* __restrict__ h, const float* __restrict__ sq,
    float* __restrict__ out)
{
    __shared__ __align__(16) unsigned short hsJ[128 * 128];   // 32 KiB
    __shared__ float sqj_s[128];                              // 512 B
    const int bid = blockIdx.x;                       // 4096 blocks
    const int xcd = bid & 7;
    const int bb  = xcd >> 1;                         // batch -> XCD pair
    const int tloc = ((bid >> 3) << 1) | (xcd & 1);   // 0..1023 tile in batch
    const int it = tloc >> 5, jt = tloc & 31;
    const int i0 = bb * 4096 + it * 128;
    const int j0 = bb * 4096 + jt * 128;
    const int t = threadIdx.x, w = t >> 6, lane = t & 63;
    const int l31 = lane & 31, lh = lane >> 5;

    const char* hb = (const char*)h;
    // reg-staged, L2-allocating j-panel load (coalesced 1 KB/wave-instr)
    f32x4 tJ[8];
    #pragma unroll
    for (int q = 0; q < 8; ++q) {
        int p   = (q * 256 + t) << 4;                 // byte off in 32 KiB panel
        int row = p >> 8;                             // 256 B per row
        tJ[q] = *(const f32x4*)(hb + ((long)(j0 + row) << 8) + (p & 255));
    }
    if (t < 128) sqj_s[t] = sq[j0 + t];
    // A-frags: wave w owns i-rows [w*32, w*32+32) (32x32x16 A layout)
    bf16x8 af[8];
    {
        const char* abase = hb + ((long)(i0 + w * 32 + l31) << 8);
        #pragma unroll
        for (int ks = 0; ks < 8; ++ks)
            af[ks] = *(const bf16x8*)(abase + ((ks * 2 + lh) << 4));
    }
    // sq_i per acc reg (C/D row = (reg&3)+8*(reg>>2)+4*lh)
    float sqi_r[16];
    #pragma unroll
    for (int reg = 0; reg < 16; ++reg)
        sqi_r[reg] = sq[i0 + w * 32 + (reg & 3) + 8 * (reg >> 2) + 4 * lh];

    #pragma unroll
    for (int q = 0; q < 8; ++q) {
        int p   = (q * 256 + t) << 4;
        int row = p >> 8;
        int c   = (p >> 4) & 15;
        int cs  = c ^ (row & 15);                     // swizzle at the WRITE
        *(f32x4*)(((char*)hsJ) + row * 256 + (cs << 4)) = tJ[q];
    }
    __syncthreads();

    const char* hJ = (const char*)hsJ;
    const bool diag = (it == jt);
    float* ob = out + ((long)i0 << 12) + (jt << 7) + l31;

    #pragma unroll
    for (int jc = 0; jc < 4; ++jc) {                  // 4 x 32-col chunks
        const int rowB = jc * 32 + l31;
        bf16x8 bg[8];
        #pragma unroll
        for (int ks = 0; ks < 8; ++ks) {
            int cB = ((ks * 2 + lh) ^ (rowB & 15)) << 4;
            bg[ks] = *(const bf16x8*)(hJ + (rowB << 8) + cB);
        }
        f32x16 acc = {};
        #pragma unroll
        for (int ks = 0; ks < 8; ++ks)
            acc = __builtin_amdgcn_mfma_f32_32x32x16_bf16(af[ks], bg[ks], acc, 0, 0, 0);

        const float sqj = sqj_s[rowB];
        #pragma unroll
        for (int reg = 0; reg < 16; ++reg) {
            const int rl = (reg & 3) + 8 * (reg >> 2) + 4 * lh;
            const int il = w * 32 + rl;
            float d2 = fmaxf(fmaf(acc[reg], -2.0f, sqi_r[reg] + sqj), 0.0f);
            float val = __expf(-__builtin_amdgcn_sqrtf(d2));
            if (diag && w == jc) {                    // wave-uniform guard
                if (rl == l31) val = 1.0f;            // exact diagonal
            }
            __builtin_nontemporal_store(val, ob + (long)il * 4096 + jc * 32);
        }
    }
}

extern "C" void kernel_launch(void* const* d_in, const int* in_sizes, int n_in,
                              void* d_out, int out_size, void* d_ws, size_t ws_size,
                              hipStream_t stream) {
    const float* x = (const float*)d_in[0];   // [4,4096,128]
    const float* W = (const float*)d_in[1];   // [128,128]
    const float* b = (const float*)d_in[2];   // [128]
    float* out = (float*)d_out;               // [4,4096,4096]

    unsigned short* h = (unsigned short*)d_ws;                       // 16384*128 bf16
    float* sq = (float*)((char*)d_ws + (size_t)16384 * 128 * 2);     // 16384 fp32

    proj_kernel<<<dim3(16384 / KA_ROWS), dim3(256), 0, stream>>>(x, W, b, h, sq);
    gram_kernel<<<dim3(4096), dim3(256), 0, stream>>>(h, sq, out);
}

// Round 22
// 68.127 us; speedup vs baseline: 1.3596x; 1.1161x over previous
//
#include <hip/hip_runtime.h>

// B=4, N=4096, D=128 fixed by the reference setup.
// d_ws layout: [0, 4MiB) h as bf16 bits (ushort), [4MiB, +64KiB) sq fp32.

typedef float  f32x4   __attribute__((ext_vector_type(4)));
typedef float  f32x16  __attribute__((ext_vector_type(16)));
typedef short  bf16x8  __attribute__((ext_vector_type(8)));

__device__ inline float bf2f(unsigned int u) {
    union { unsigned int i; float f; } c; c.i = u << 16; return c.f;
}
__device__ inline unsigned short f2bf(float f) {
    union { float f; unsigned int i; } c; c.f = f;
    unsigned int r = c.i + 0x7fffu + ((c.i >> 16) & 1u);   // RNE
    return (unsigned short)(r >> 16);
}

// ---------------- Kernel A: h = bf16(x @ W^T + b), plus sq[row] = ||h_row||^2 ----
#define KA_ROWS 32
__global__ __launch_bounds__(256) void proj_kernel(
    const float* __restrict__ x, const float* __restrict__ W,
    const float* __restrict__ bias, unsigned short* __restrict__ h,
    float* __restrict__ sq)
{
    __shared__ __align__(16) unsigned short W5[32 * 4 * 32 * 4]; // 32 KiB
    __shared__ float xs[KA_ROWS][132];
    const int t = threadIdx.x;
    const long r0 = (long)blockIdx.x * KA_ROWS;

    for (int q = t; q < 4096; q += 256) {
        float4 w4 = ((const float4*)W)[q];
        int e = q >> 5, d4 = q & 31;
        int eb = e >> 2, ei = e & 3;
        ushort4 o;
        o.x = f2bf(w4.x); o.y = f2bf(w4.y); o.z = f2bf(w4.z); o.w = f2bf(w4.w);
        *(ushort4*)&W5[d4 * 256 + ei * 64 + ((eb ^ d4) & 31) * 4] = o;
    }
    const float4* xsrc = (const float4*)(x + r0 * 128);
    for (int q = t; q < KA_ROWS * 32; q += 256) {
        float4 v = xsrc[q];
        int r = q >> 5, d = (q & 31) << 2;
        xs[r][d] = v.x; xs[r][d + 1] = v.y; xs[r][d + 2] = v.z; xs[r][d + 3] = v.w;
    }
    __syncthreads();

    const int eb = t & 31, rb = t >> 5;
    const int e0 = eb * 4, rr0 = rb * 4;

    float acc_[4][4];
    #pragma unroll
    for (int ei = 0; ei < 4; ++ei) {
        float bv = bias[e0 + ei];
        #pragma unroll
        for (int ri = 0; ri < 4; ++ri) acc_[ri][ei] = bv;
    }

    for (int d4 = 0; d4 < 32; ++d4) {
        float wv[4][4];
        #pragma unroll
        for (int ei = 0; ei < 4; ++ei) {
            ushort4 u = *(const ushort4*)&W5[d4 * 256 + ei * 64 + ((eb ^ d4) & 31) * 4];
            wv[ei][0] = bf2f(u.x); wv[ei][1] = bf2f(u.y);
            wv[ei][2] = bf2f(u.z); wv[ei][3] = bf2f(u.w);
        }
        #pragma unroll
        for (int ri = 0; ri < 4; ++ri) {
            float4 xv = *(const float4*)&xs[rr0 + ri][d4 * 4];
            #pragma unroll
            for (int ei = 0; ei < 4; ++ei) {
                acc_[ri][ei] = fmaf(xv.x, wv[ei][0],
                               fmaf(xv.y, wv[ei][1],
                               fmaf(xv.z, wv[ei][2],
                               fmaf(xv.w, wv[ei][3], acc_[ri][ei]))));
            }
        }
    }

    float s[4] = {0.f, 0.f, 0.f, 0.f};
    #pragma unroll
    for (int ri = 0; ri < 4; ++ri) {
        ushort4 o;
        float v0 = bf2f(o.x = f2bf(acc_[ri][0]));
        float v1 = bf2f(o.y = f2bf(acc_[ri][1]));
        float v2 = bf2f(o.z = f2bf(acc_[ri][2]));
        float v3 = bf2f(o.w = f2bf(acc_[ri][3]));
        s[ri] = v0 * v0 + v1 * v1 + v2 * v2 + v3 * v3;
        *(ushort4*)&h[(r0 + rr0 + ri) * 128 + e0] = o;
    }
    #pragma unroll
    for (int ri = 0; ri < 4; ++ri) {
        #pragma unroll
        for (int m = 16; m > 0; m >>= 1) s[ri] += __shfl_xor(s[ri], m, 64);
    }
    if (eb == 0) {
        #pragma unroll
        for (int ri = 0; ri < 4; ++ri) sq[r0 + rr0 + ri] = s[ri];
    }
}

// ---------------- Kernel B: R19 champion + epilogue VALU diet ------------------
// Identical to the 68.7 µs champion (128x128 tile, 2 blocks/CU, reg-staged
// L2-allocating loads, both-sides swizzle, XCD affinity, vmcnt-clean
// epilogue, nt stores, one barrier) EXCEPT the epilogue math:
//   exp(-d) = exp2(-sqrt(d2 * log2e^2)): sq pre-scaled by log2e^2 at LDS
//   stage, fma const -2*log2e^2 -> the -log2e mul disappears (exp2 input
//   negation is a free VOP modifier). fmax dropped: d2<0 only on the exact
//   diagonal, whose NaN is overwritten by the 1.0 cndmask anyway.
// Per-element: 4 VALU + 2 trans -> 2 VALU + 2 trans.
#define L2E2 2.0813689810056077f      // (log2 e)^2
__global__ __launch_bounds__(256, 2) void gram_kernel(
    const unsigned short* __restrict__ h, const float* __restrict__ sq,
    float* __restrict__ out)
{
    __shared__ __align__(16) unsigned short hsI[128 * 128];   // 32 KiB
    __shared__ __align__(16) unsigned short hsJ[128 * 128];   // 32 KiB
    __shared__ float sqs[256];                                // [0,128)=i, [128,256)=j
    const int bid = blockIdx.x;                       // 4096 blocks
    const int xcd = bid & 7;
    const int bb  = xcd >> 1;                         // batch -> XCD pair
    const int tloc = ((bid >> 3) << 1) | (xcd & 1);   // 0..1023 tile in batch
    const int it = tloc >> 5, jt = tloc & 31;
    const int i0 = bb * 4096 + it * 128;
    const int j0 = bb * 4096 + jt * 128;
    const int t = threadIdx.x, w = t >> 6, lane = t & 63;

    const char* hb = (const char*)h;
    // reg-staged, L2-allocating panel loads (coalesced 1 KB/wave-instr)
    f32x4 tI[8], tJ[8];
    #pragma unroll
    for (int q = 0; q < 8; ++q) {
        int p   = (q * 256 + t) << 4;                 // byte off in 32 KiB panel
        int row = p >> 8;                             // 256 B per row
        tI[q] = *(const f32x4*)(hb + ((long)(i0 + row) << 8) + (p & 255));
        tJ[q] = *(const f32x4*)(hb + ((long)(j0 + row) << 8) + (p & 255));
    }
    sqs[t] = sq[((t >> 7) ? j0 - 128 : i0) + t] * L2E2;   // pre-scaled
    #pragma unroll
    for (int q = 0; q < 8; ++q) {
        int p   = (q * 256 + t) << 4;
        int row = p >> 8;
        int c   = (p >> 4) & 15;
        int cs  = c ^ (row & 15);                     // swizzle at the WRITE
        *(f32x4*)(((char*)hsI) + row * 256 + (cs << 4)) = tI[q];
        *(f32x4*)(((char*)hsJ) + row * 256 + (cs << 4)) = tJ[q];
    }
    __syncthreads();

    const int wr = w >> 1, wc = w & 1;      // wave -> 64x64 quadrant
    const int l31 = lane & 31, lh = lane >> 5;
    f32x16 acc[2][2] = {};
    const char* hI = (const char*)hsI;
    const char* hJ = (const char*)hsJ;

    #pragma unroll
    for (int ks = 0; ks < 8; ++ks) {        // K = 8 x 16
        bf16x8 af[2], bg[2];
        #pragma unroll
        for (int rb = 0; rb < 2; ++rb) {
            int rowA = wr * 64 + rb * 32 + l31;
            int cA = ((ks * 2 + lh) ^ (rowA & 15)) << 4;
            af[rb] = *(const bf16x8*)(hI + (rowA << 8) + cA);
            int rowB = wc * 64 + rb * 32 + l31;
            int cB = ((ks * 2 + lh) ^ (rowB & 15)) << 4;
            bg[rb] = *(const bf16x8*)(hJ + (rowB << 8) + cB);
        }
        #pragma unroll
        for (int rb = 0; rb < 2; ++rb)
            #pragma unroll
            for (int nb = 0; nb < 2; ++nb)
                acc[rb][nb] = __builtin_amdgcn_mfma_f32_32x32x16_bf16(
                    af[rb], bg[nb], acc[rb][nb], 0, 0, 0);
    }

    // epilogue: ZERO global loads; 2 VALU + 2 trans per element
    float sqj_r[2];
    #pragma unroll
    for (int nb = 0; nb < 2; ++nb) sqj_r[nb] = sqs[128 + wc * 64 + nb * 32 + l31];

    #pragma unroll
    for (int rb = 0; rb < 2; ++rb) {
        #pragma unroll
        for (int reg = 0; reg < 16; ++reg) {
            int il = wr * 64 + rb * 32 + (reg & 3) + 8 * (reg >> 2) + 4 * lh;
            float sqi_v = sqs[il];                    // LDS broadcast
            #pragma unroll
            for (int nb = 0; nb < 2; ++nb) {
                int jl = wc * 64 + nb * 32 + l31;
                float d2 = fmaf(acc[rb][nb][reg], -2.0f * L2E2, sqi_v + sqj_r[nb]);
                float val = __builtin_amdgcn_exp2f(-__builtin_amdgcn_sqrtf(d2));
                if (it == jt && il == jl) val = 1.0f;     // exact diagonal (kills NaN)
                __builtin_nontemporal_store(
                    val, &out[((long)(i0 + il) << 12) + (jt << 7) + jl]);
            }
        }
    }
}

extern "C" void kernel_launch(void* const* d_in, const int* in_sizes, int n_in,
                              void* d_out, int out_size, void* d_ws, size_t ws_size,
                              hipStream_t stream) {
    const float* x = (const float*)d_in[0];   // [4,4096,128]
    const float* W = (const float*)d_in[1];   // [128,128]
    const float* b = (const float*)d_in[2];   // [128]
    float* out = (float*)d_out;               // [4,4096,4096]

    unsigned short* h = (unsigned short*)d_ws;                       // 16384*128 bf16
    float* sq = (float*)((char*)d_ws + (size_t)16384 * 128 * 2);     // 16384 fp32

    proj_kernel<<<dim3(16384 / KA_ROWS), dim3(256), 0, stream>>>(x, W, b, h, sq);
    gram_kernel<<<dim3(4096), dim3(256), 0, stream>>>(h, sq, out);
}